// Round 21
// baseline (334.206 us; speedup 1.0000x reference)
//
#include <hip/hip_runtime.h>
#include <stdint.h>

#define NN 100000
#define EE 1600000
#define DD 64
#define NBUCK 391        // ceil(NN/256): bucket b covers nodes [b*256, b*256+255]
#define SCWG 200         // hist/scatter workgroups; 8000 edges each
#define SCCHUNK 8000

using short8 = __attribute__((ext_vector_type(8))) short;
using f32x4  = __attribute__((ext_vector_type(4))) float;
using f2     = __attribute__((ext_vector_type(2))) float;

// ---------------- bf16 helpers ----------------

__device__ __forceinline__ unsigned short bf16_rne(float f) {
    unsigned int u = __float_as_uint(f);
    unsigned int r = (u + 0x7FFFu + ((u >> 16) & 1u)) >> 16;
    return (unsigned short)r;
}
__device__ __forceinline__ float bf16_to_f32(unsigned short h) {
    return __uint_as_float(((unsigned int)h) << 16);
}
__device__ __forceinline__ void unpack4(uint2 u, f2& v01, f2& v23) {
    v01 = f2{ __uint_as_float(u.x << 16), __uint_as_float(u.x & 0xFFFF0000u) };
    v23 = f2{ __uint_as_float(u.y << 16), __uint_as_float(u.y & 0xFFFF0000u) };
}

// ---------------- fused histogram (per-block partials, no atomics) + conversions ----------------

__global__ void hist_conv(const int* __restrict__ dst, int* __restrict__ bhistPart,
                          const float* __restrict__ Wl, const float* __restrict__ Wr,
                          const float* __restrict__ Ws, const float* __restrict__ x,
                          unsigned short* __restrict__ Wt_hi, unsigned short* __restrict__ Wt_lo,
                          unsigned short* __restrict__ Ahi) {
    int b = blockIdx.x;
    int t = threadIdx.x;
    if (b < SCWG) {
        __shared__ int h[NBUCK];
        for (int i = t; i < NBUCK; i += 256) h[i] = 0;
        __syncthreads();
        int start = b * SCCHUNK;
        int endi = min(start + SCCHUNK, EE);
        for (int e = start + t; e < endi; e += 256)
            atomicAdd(&h[dst[e] >> 8], 1);
        __syncthreads();
        for (int i = t; i < NBUCK; i += 256)
            bhistPart[b * NBUCK + i] = h[i];               // coalesced, non-atomic
    } else if (b < SCWG + 144) {
        int e = (b - SCWG) * 256 + t;
        if (e >= 9 * 4096) return;
        int mat = e >> 12;          // 0..8 = L*3 + j
        int r   = e & 4095;
        int k   = r >> 6, n = r & 63;
        int L = mat / 3, j = mat % 3;
        const float* W = (j == 0) ? Wl : ((j == 1) ? Wr : Ws);
        float v = W[L * 4096 + k * 64 + n];
        unsigned short hi = bf16_rne(v);
        unsigned short lo = bf16_rne(v - bf16_to_f32(hi));
        Wt_hi[mat * 4096 + n * 64 + k] = hi;
        Wt_lo[mat * 4096 + n * 64 + k] = lo;
    } else {
        int i = (b - SCWG - 144) * 256 + t;                // one float4 per thread
        int total = NN * 16;
        int stride = (gridDim.x - SCWG - 144) * 256;
        for (; i < total; i += stride) {
            float4 v = *(const float4*)&x[(size_t)i * 4];
            ushort4 h;
            h.x = bf16_rne(v.x);
            h.y = bf16_rne(v.y);
            h.z = bf16_rne(v.z);
            h.w = bf16_rne(v.w);
            *(ushort4*)&Ahi[(size_t)i * 4] = h;
        }
    }
}

// ---------------- scatter with self-computed scan (fully deterministic, no global atomics) ----------------
// Each block computes: sbase[i] = exclusive_scan_i( sum_w part[w][i] ),
//                      lcur[i]  = sbase[i] + sum_{w<b} part[w][i]
// Block 0 also emits bbase / offsets[NN] for bucket_csr.

__global__ __launch_bounds__(256) void bucket_scatter(
    const int* __restrict__ src, const int* __restrict__ dst,
    const int* __restrict__ bhistPart, int* __restrict__ bbase,
    unsigned int* __restrict__ bedges, int* __restrict__ offsets) {
    __shared__ int s[512];
    __shared__ int lcur[NBUCK];
    int t = threadIdx.x;
    int b = blockIdx.x;
    int i0 = t, i1 = t + 256;

    int tot0 = 0, pre0 = 0, tot1 = 0, pre1 = 0;
    if (i0 < NBUCK) {
        for (int w = 0; w < SCWG; w++) {
            int c = bhistPart[w * NBUCK + i0];
            tot0 += c;
            if (w < b) pre0 += c;
        }
    }
    if (i1 < NBUCK) {
        for (int w = 0; w < SCWG; w++) {
            int c = bhistPart[w * NBUCK + i1];
            tot1 += c;
            if (w < b) pre1 += c;
        }
    }
    s[i0] = tot0;
    s[i1] = tot1;
    __syncthreads();
    for (int off = 1; off < 512; off <<= 1) {
        int a0 = (i0 >= off) ? s[i0 - off] : 0;
        int a1 = (i1 >= off) ? s[i1 - off] : 0;
        __syncthreads();
        s[i0] += a0;
        s[i1] += a1;
        __syncthreads();
    }
    if (i0 < NBUCK) {
        int excl = s[i0] - tot0;
        lcur[i0] = excl + pre0;
        if (b == 0) bbase[i0] = excl;
    }
    if (i1 < NBUCK) {
        int excl = s[i1] - tot1;
        lcur[i1] = excl + pre1;
        if (b == 0) bbase[i1] = excl;
    }
    if (b == 0 && t == 0) { bbase[NBUCK] = EE; offsets[NN] = EE; }
    __syncthreads();

    int start = b * SCCHUNK;
    int endi = min(start + SCCHUNK, EE);
    for (int e = start + t; e < endi; e += 256) {
        int d = dst[e];
        int pos = atomicAdd(&lcur[d >> 8], 1);
        bedges[pos] = ((unsigned int)(d & 255) << 24) | (unsigned int)src[e];
    }
}

__global__ void bucket_csr(const unsigned int* __restrict__ bedges, const int* __restrict__ bbase,
                           int* __restrict__ offsets, int* __restrict__ csr) {
    __shared__ int ncnt[256];
    __shared__ int lofs[256];
    int b = blockIdx.x;
    int t = threadIdx.x;
    int beg = bbase[b], endb = bbase[b + 1];
    ncnt[t] = 0;
    __syncthreads();
    for (int e = beg + t; e < endb; e += 256)
        atomicAdd(&ncnt[bedges[e] >> 24], 1);
    __syncthreads();
    int v = ncnt[t];
    lofs[t] = v;
    __syncthreads();
    for (int off = 1; off < 256; off <<= 1) {
        int a = (t >= off) ? lofs[t - off] : 0;
        __syncthreads();
        lofs[t] += a;
        __syncthreads();
    }
    int excl = lofs[t] - v;
    int node = b * 256 + t;
    if (node < NN) offsets[node] = beg + excl;
    __syncthreads();
    ncnt[t] = beg + excl;                  // reuse as cursor
    __syncthreads();
    for (int e = beg + t; e < endb; e += 256) {
        unsigned int ed = bedges[e];
        int pos = atomicAdd(&ncnt[ed >> 24], 1);
        csr[pos] = (int)(ed & 0xFFFFFFu);
    }
}

// ---------------- MFMA GEMM: A bf16 x split-bf16 W, 32 rows/wave (unchanged) ----------------

__global__ __launch_bounds__(256) void gemm_mfma(
    const unsigned short* __restrict__ Ahi,
    const unsigned short* __restrict__ Wt_hi, const unsigned short* __restrict__ Wt_lo,
    const float* __restrict__ bl, const float* __restrict__ br, const float* __restrict__ bs,
    unsigned short* __restrict__ Xlb, unsigned short* __restrict__ XRS) {
    int lane = threadIdx.x & 63;
    int wid  = threadIdx.x >> 6;
    int m0 = (blockIdx.x * 4 + wid) * 32;
    if (m0 >= NN) return;

    int l4 = lane & 15;
    int hi = lane >> 4;
    int koff = hi * 8;

    int arow0 = m0 + l4, arow1 = m0 + 16 + l4;
    bool ok0 = arow0 < NN, ok1 = arow1 < NN;
    int ar0 = ok0 ? arow0 : NN - 1;
    int ar1 = ok1 ? arow1 : NN - 1;

    const unsigned short* ab0 = Ahi + (size_t)ar0 * 64;
    const unsigned short* ab1 = Ahi + (size_t)ar1 * 64;
    short8 a0k0 = *(const short8*)(ab0 + koff);
    short8 a0k1 = *(const short8*)(ab0 + 32 + koff);
    short8 a1k0 = *(const short8*)(ab1 + koff);
    short8 a1k1 = *(const short8*)(ab1 + 32 + koff);

    int nbase0 = hi * 4;

#pragma unroll
    for (int m = 0; m < 3; m++) {
        const unsigned short* wh = Wt_hi + m * 4096;
        const unsigned short* wl = Wt_lo + m * 4096;
        const float* bias = (m == 0) ? bl : ((m == 1) ? br : bs);
#pragma unroll
        for (int tt = 0; tt < 4; tt++) {
            int ncol = tt * 16 + l4;                  // weight load row
            const unsigned short* bh = wh + ncol * 64 + koff;
            const unsigned short* blo = wl + ncol * 64 + koff;
            short8 bhi0 = *(const short8*)bh;
            short8 bhi1 = *(const short8*)(bh + 32);
            short8 blo0 = *(const short8*)blo;
            short8 blo1 = *(const short8*)(blo + 32);

            f32x4 acc0 = {0.f, 0.f, 0.f, 0.f};
            f32x4 acc1 = {0.f, 0.f, 0.f, 0.f};
            acc0 = __builtin_amdgcn_mfma_f32_16x16x32_bf16(bhi0, a0k0, acc0, 0, 0, 0);
            acc1 = __builtin_amdgcn_mfma_f32_16x16x32_bf16(bhi0, a1k0, acc1, 0, 0, 0);
            acc0 = __builtin_amdgcn_mfma_f32_16x16x32_bf16(bhi1, a0k1, acc0, 0, 0, 0);
            acc1 = __builtin_amdgcn_mfma_f32_16x16x32_bf16(bhi1, a1k1, acc1, 0, 0, 0);
            acc0 = __builtin_amdgcn_mfma_f32_16x16x32_bf16(blo0, a0k0, acc0, 0, 0, 0);
            acc1 = __builtin_amdgcn_mfma_f32_16x16x32_bf16(blo0, a1k0, acc1, 0, 0, 0);
            acc0 = __builtin_amdgcn_mfma_f32_16x16x32_bf16(blo1, a0k1, acc0, 0, 0, 0);
            acc1 = __builtin_amdgcn_mfma_f32_16x16x32_bf16(blo1, a1k1, acc1, 0, 0, 0);

            int nb = tt * 16 + nbase0;                // first of 4 consecutive output cols
            float4 bb = *(const float4*)&bias[nb];
            ushort4 h0, h1;
            h0.x = bf16_rne(acc0[0] + bb.x); h0.y = bf16_rne(acc0[1] + bb.y);
            h0.z = bf16_rne(acc0[2] + bb.z); h0.w = bf16_rne(acc0[3] + bb.w);
            h1.x = bf16_rne(acc1[0] + bb.x); h1.y = bf16_rne(acc1[1] + bb.y);
            h1.z = bf16_rne(acc1[2] + bb.z); h1.w = bf16_rne(acc1[3] + bb.w);
            if (m == 0) {
                if (ok0) *(ushort4*)&Xlb[(size_t)ar0 * 64 + nb] = h0;
                if (ok1) *(ushort4*)&Xlb[(size_t)ar1 * 64 + nb] = h1;
            } else {
                int coff = (m == 1) ? 0 : 64;
                if (ok0) *(ushort4*)&XRS[(size_t)ar0 * 128 + coff + nb] = h0;
                if (ok1) *(ushort4*)&XRS[(size_t)ar1 * 128 + coff + nb] = h1;
            }
        }
    }
}

// ---------------- per-node attention aggregation (R12/R18 structure, unchanged) ----------------

__device__ __forceinline__ float group_sum16(float t) {
    t += __int_as_float(__builtin_amdgcn_update_dpp(0, __float_as_int(t), 0xB1, 0xF, 0xF, true));   // xor1
    t += __int_as_float(__builtin_amdgcn_update_dpp(0, __float_as_int(t), 0x4E, 0xF, 0xF, true));   // xor2
    t += __int_as_float(__builtin_amdgcn_update_dpp(0, __float_as_int(t), 0x141, 0xF, 0xF, true));  // row_half_mirror ~ xor4
    t += __int_as_float(__builtin_amdgcn_update_dpp(0, __float_as_int(t), 0x140, 0xF, 0xF, true));  // row_mirror ~ xor8
    return t;
}

__global__ __launch_bounds__(256) void node_kernel(
    const unsigned short* __restrict__ Xlb, const unsigned short* __restrict__ XRS,
    const int* __restrict__ offsets, const int* __restrict__ csr,
    const float* __restrict__ att, const float* __restrict__ bg,
    unsigned short* __restrict__ hout, int do_relu,
    const float* __restrict__ Wout, const float* __restrict__ bout,
    float* __restrict__ outp, int do_out) {
    int lane = threadIdx.x & 63;
    int wid  = threadIdx.x >> 6;
    int i = blockIdx.x * 4 + wid;
    if (i >= NN) return;
    int sub = lane & 15;
    int grp = lane >> 4;

    f2 xr01, xr23;
    unpack4(*(const uint2*)&XRS[(size_t)i * 128 + sub * 4], xr01, xr23);
    float4 att4 = *(const float4*)&att[sub * 4];
    f2 at01 = {att4.x, att4.y}, at23 = {att4.z, att4.w};

    f2 agg01 = {0.f, 0.f}, agg23 = {0.f, 0.f};
    float denom = 0.f;
    int beg = offsets[i], end = offsets[i + 1];

    for (int j0 = beg; j0 < end; j0 += 8) {
        int jA = j0 + grp, jB = jA + 4;
        bool vA = jA < end, vB = jB < end;
        int sA = csr[vA ? jA : beg];
        int sB = csr[vB ? jB : beg];
        uint2 uA = *(const uint2*)&Xlb[(size_t)sA * 64 + sub * 4];
        uint2 uB = *(const uint2*)&Xlb[(size_t)sB * 64 + sub * 4];
        f2 xA01, xA23, xB01, xB23;
        unpack4(uA, xA01, xA23);
        unpack4(uB, xB01, xB23);

        f2 sA01 = xA01 + xr01;                 // v_pk_add_f32
        f2 sA23 = xA23 + xr23;
        f2 sB01 = xB01 + xr01;
        f2 sB23 = xB23 + xr23;
        f2 lA01 = { fmaxf(sA01.x, 0.2f * sA01.x), fmaxf(sA01.y, 0.2f * sA01.y) };
        f2 lA23 = { fmaxf(sA23.x, 0.2f * sA23.x), fmaxf(sA23.y, 0.2f * sA23.y) };
        f2 lB01 = { fmaxf(sB01.x, 0.2f * sB01.x), fmaxf(sB01.y, 0.2f * sB01.y) };
        f2 lB23 = { fmaxf(sB23.x, 0.2f * sB23.x), fmaxf(sB23.y, 0.2f * sB23.y) };

        f2 tAv = lA01 * at01 + lA23 * at23;    // pk_mul + pk_fma
        f2 tBv = lB01 * at01 + lB23 * at23;
        float tA = group_sum16(tAv.x + tAv.y);
        float tB = group_sum16(tBv.x + tBv.y);
        float aA = vA ? __expf(tA) : 0.f;
        float aB = vB ? __expf(tB) : 0.f;

        f2 aAv = {aA, aA};
        f2 aBv = {aB, aB};
        agg01 += aAv * xA01 + aBv * xB01;      // pk_fma chain
        agg23 += aAv * xA23 + aBv * xB23;
        denom += aA + aB;
    }

    float aggx = agg01.x, aggy = agg01.y, aggz = agg23.x, aggw = agg23.y;
#pragma unroll
    for (int m = 16; m <= 32; m <<= 1) {
        aggx  += __shfl_xor(aggx, m, 64);
        aggy  += __shfl_xor(aggy, m, 64);
        aggz  += __shfl_xor(aggz, m, 64);
        aggw  += __shfl_xor(aggw, m, 64);
        denom += __shfl_xor(denom, m, 64);
    }

    float inv = (denom > 0.f) ? (1.0f / denom) : 0.f;
    f2 sk01, sk23;
    unpack4(*(const uint2*)&XRS[(size_t)i * 128 + 64 + sub * 4], sk01, sk23);
    float4 bg4 = *(const float4*)&bg[sub * 4];
    float4 res;
    res.x = aggx * inv + bg4.x + sk01.x;
    res.y = aggy * inv + bg4.y + sk01.y;
    res.z = aggz * inv + bg4.z + sk23.x;
    res.w = aggw * inv + bg4.w + sk23.y;
    if (do_relu) {
        res.x = fmaxf(res.x, 0.f); res.y = fmaxf(res.y, 0.f);
        res.z = fmaxf(res.z, 0.f); res.w = fmaxf(res.w, 0.f);
    }
    if (do_out) {
        float4 w01 = *(const float4*)&Wout[8 * sub];
        float4 w23 = *(const float4*)&Wout[8 * sub + 4];
        float o0 = res.x * w01.x + res.y * w01.z + res.z * w23.x + res.w * w23.z;
        float o1 = res.x * w01.y + res.y * w01.w + res.z * w23.y + res.w * w23.w;
        o0 = group_sum16(o0);
        o1 = group_sum16(o1);
        if (lane == 0) {
            outp[(size_t)i * 2 + 0] = o0 + bout[0];
            outp[(size_t)i * 2 + 1] = o1 + bout[1];
        }
    } else {
        if (grp == 0) {
            ushort4 h;
            h.x = bf16_rne(res.x);
            h.y = bf16_rne(res.y);
            h.z = bf16_rne(res.z);
            h.w = bf16_rne(res.w);
            *(ushort4*)&hout[(size_t)i * 64 + sub * 4] = h;
        }
    }
}

// ---------------- launch ----------------

extern "C" void kernel_launch(void* const* d_in, const int* in_sizes, int n_in,
                              void* d_out, int out_size, void* d_ws, size_t ws_size,
                              hipStream_t stream) {
    const float* x    = (const float*)d_in[0];
    const int*   ei   = (const int*)d_in[1];
    const float* Wl   = (const float*)d_in[2];
    const float* bl   = (const float*)d_in[3];
    const float* Wr   = (const float*)d_in[4];
    const float* br   = (const float*)d_in[5];
    const float* att  = (const float*)d_in[6];
    const float* bg   = (const float*)d_in[7];
    const float* Ws   = (const float*)d_in[8];
    const float* bs   = (const float*)d_in[9];
    const float* Wout = (const float*)d_in[10];
    const float* bout = (const float*)d_in[11];
    float* out = (float*)d_out;

    size_t off = 0;
    char* base = (char*)d_ws;
    auto alloc = [&](size_t bytes) -> void* {
        void* p = base + off;
        off += (bytes + 255) & ~(size_t)255;
        return p;
    };
    unsigned short* Xlb = (unsigned short*)alloc((size_t)NN * 64 * 2);
    unsigned short* XRS = (unsigned short*)alloc((size_t)NN * 128 * 2);
    unsigned short* Ahi = (unsigned short*)alloc((size_t)NN * 64 * 2);
    unsigned short* Bhi = (unsigned short*)alloc((size_t)NN * 64 * 2);
    unsigned short* Wthi = (unsigned short*)alloc((size_t)9 * 4096 * 2);
    unsigned short* Wtlo = (unsigned short*)alloc((size_t)9 * 4096 * 2);
    int*  bhistPart = (int*)alloc((size_t)SCWG * NBUCK * 4);
    int*  bbase  = (int*)alloc((size_t)(NBUCK + 1) * 4);
    unsigned int* bedges = (unsigned int*)alloc((size_t)EE * 4);
    int*  offs   = (int*)alloc((size_t)(NN + 1) * 4);
    int*  csr    = (int*)alloc((size_t)EE * 4);

    const int* src = ei;
    const int* dst = ei + EE;

    hist_conv<<<SCWG + 144 + 400, 256, 0, stream>>>(dst, bhistPart, Wl, Wr, Ws, x,
                                                    Wthi, Wtlo, Ahi);
    bucket_scatter<<<SCWG, 256, 0, stream>>>(src, dst, bhistPart, bbase, bedges, offs);
    bucket_csr<<<NBUCK, 256, 0, stream>>>(bedges, bbase, offs, csr);

    unsigned short* cur = Ahi;
    unsigned short* nxt = Bhi;
    for (int L = 0; L < 3; L++) {
        gemm_mfma<<<(NN + 127) / 128, 256, 0, stream>>>(
            cur, Wthi + (size_t)L * 3 * 4096, Wtlo + (size_t)L * 3 * 4096,
            bl + L * 64, br + L * 64, bs + L * 64, Xlb, XRS);
        node_kernel<<<NN / 4, 256, 0, stream>>>(
            Xlb, XRS, offs, csr, att + L * 64, bg + L * 64,
            nxt, (L < 2) ? 1 : 0,
            Wout, bout, out, (L == 2) ? 1 : 0);
        unsigned short* tp = cur; cur = nxt; nxt = tp;
    }
}